// Round 1
// baseline (599.467 us; speedup 1.0000x reference)
//
#include <hip/hip_runtime.h>
#include <hip/hip_bf16.h>
#include <math.h>

// LinearAttention: B=8, DIM=256, HEADS=8, DHEAD=64, HID=512, n=4096
// Round 0 baseline: fp32 tiled GEMMs, bf16 intermediates (tolerance is ~2% rel).
// Pipeline:
//   K1: qkv = Wqkv @ x  (per batch 1536x256 @ 256x4096), fused elu1 + contact gate,
//       store q/k/v bf16 to ws
//   K2: kv[b,h,64,64] = k @ v^T over n, ksum[b,h,64] (split-n + fp32 atomics)
//   K3: out[b,hid,n] = z * kv^T q   (z = 1/(q . ksum + 1e-6)), bf16 to ws
//   K4: y = Wout @ out + bout  (per batch 256x512 @ 512x4096), fp32 to d_out

#define DIMC 256
#define HEADS 8
#define DHEAD 64
#define HIDC 512
#define BATCH 8
#define NPIX 4096

__device__ __forceinline__ float bf2f(unsigned short h) {
    unsigned int u = ((unsigned int)h) << 16;
    float f;
    __builtin_memcpy(&f, &u, 4);
    return f;
}
__device__ __forceinline__ unsigned short f2bf(float f) {
    unsigned int u;
    __builtin_memcpy(&u, &f, 4);
    unsigned int lsb = (u >> 16) & 1u;
    u += 0x7fffu + lsb;           // round to nearest even
    return (unsigned short)(u >> 16);
}
__device__ __forceinline__ float elu1(float x) {
    return x > 0.f ? x + 1.f : __expf(x);
}

// ---------------- K1: qkv GEMM + activation epilogue ----------------
// grid (32, 12, 8), block 256. C tile 128x128, 8x8 per thread, BK=16.
__global__ __launch_bounds__(256) void k_qkv(
    const float* __restrict__ W,     // 1536 x 256
    const float* __restrict__ x,     // B x 256 x 4096
    const float* __restrict__ cmp,   // B x 4096
    const float* __restrict__ csp,   // scalar
    unsigned short* __restrict__ qb,
    unsigned short* __restrict__ kb,
    unsigned short* __restrict__ vb)
{
    const int b  = blockIdx.z;
    const int m0 = blockIdx.y * 128;
    const int n0 = blockIdx.x * 128;
    const int t  = threadIdx.x;
    const int tr = t >> 4, tc = t & 15;

    __shared__ float As[16][132];   // [k][m], padded: stride 132 -> 2-way max
    __shared__ float Bs[16][128];   // [k][n]

    const float* A = W;
    const float* B = x + (size_t)b * DIMC * NPIX;

    float acc[8][8];
#pragma unroll
    for (int i = 0; i < 8; i++)
#pragma unroll
        for (int j = 0; j < 8; j++) acc[i][j] = 0.f;

    for (int k0 = 0; k0 < DIMC; k0 += 16) {
        // A tile 128x16 (row-major lda=256) -> As transposed
#pragma unroll
        for (int i = 0; i < 2; i++) {
            int idx = t + i * 256;          // 0..511 float4s
            int m = idx >> 2;
            int kq = idx & 3;
            const float4 av = *(const float4*)(A + (size_t)(m0 + m) * DIMC + k0 + kq * 4);
            As[kq * 4 + 0][m] = av.x;
            As[kq * 4 + 1][m] = av.y;
            As[kq * 4 + 2][m] = av.z;
            As[kq * 4 + 3][m] = av.w;
        }
        // B tile 16x128 (row-major ldb=4096)
#pragma unroll
        for (int i = 0; i < 2; i++) {
            int idx = t + i * 256;
            int kk = idx >> 5;
            int n4 = idx & 31;
            const float4 bv = *(const float4*)(B + (size_t)(k0 + kk) * NPIX + n0 + n4 * 4);
            *(float4*)(&Bs[kk][n4 * 4]) = bv;
        }
        __syncthreads();
#pragma unroll
        for (int kk = 0; kk < 16; kk++) {
            float a[8], bb[8];
            *(float4*)(a)     = *(const float4*)(&As[kk][tr * 8]);
            *(float4*)(a + 4) = *(const float4*)(&As[kk][tr * 8 + 4]);
            *(float4*)(bb)     = *(const float4*)(&Bs[kk][tc * 8]);
            *(float4*)(bb + 4) = *(const float4*)(&Bs[kk][tc * 8 + 4]);
#pragma unroll
            for (int i = 0; i < 8; i++)
#pragma unroll
                for (int j = 0; j < 8; j++)
                    acc[i][j] = fmaf(a[i], bb[j], acc[i][j]);
        }
        __syncthreads();
    }

    // epilogue: section uniform per block (m0 multiple of 128, 512/128=4)
    const int sect = m0 / HIDC;       // 0=q, 1=k, 2=v
    const float cs = *csp;
    const int ncol = n0 + tc * 8;

    float cmv[8];
    if (sect == 1) {
#pragma unroll
        for (int j = 0; j < 8; j++)
            cmv[j] = 1.f + cs * cmp[(size_t)b * NPIX + ncol + j];
    }

    unsigned short* dstbase = (sect == 0) ? qb : (sect == 1 ? kb : vb);
#pragma unroll
    for (int i = 0; i < 8; i++) {
        int row = m0 + tr * 8 + i;
        int hid = row & (HIDC - 1);
        float vals[8];
#pragma unroll
        for (int j = 0; j < 8; j++) vals[j] = acc[i][j];
        if (sect == 0) {
#pragma unroll
            for (int j = 0; j < 8; j++) vals[j] = elu1(vals[j]);
        } else if (sect == 1) {
#pragma unroll
            for (int j = 0; j < 8; j++) vals[j] = elu1(vals[j]) * cmv[j];
        }
        unsigned short hs[8];
#pragma unroll
        for (int j = 0; j < 8; j++) hs[j] = f2bf(vals[j]);
        unsigned short* dst = dstbase + ((size_t)b * HIDC + hid) * NPIX + ncol;
        *(uint4*)dst = *(const uint4*)hs;   // 16B store, aligned
    }
}

// ---------------- K2: kv + ksum reduction ----------------
// grid (8 nchunks, 8 h, 8 b), block 256. Each block: 512 columns.
__global__ __launch_bounds__(256) void k_kv(
    const unsigned short* __restrict__ kb,
    const unsigned short* __restrict__ vb,
    float* __restrict__ kv,      // B*H x 64 x 64  (zeroed)
    float* __restrict__ ksum)    // B*H x 64       (zeroed)
{
    const int b = blockIdx.z, h = blockIdx.y, nc = blockIdx.x;
    const int t = threadIdx.x;
    const int tr = t >> 4, tc = t & 15;   // d-group, e-group

    __shared__ float ks[64][33];
    __shared__ float vs[64][33];

    const size_t base = ((size_t)b * HIDC + h * 64) * NPIX;
    float acc[4][4] = {{0}};
    float ksacc[4] = {0, 0, 0, 0};

    for (int nn0 = nc * 512; nn0 < nc * 512 + 512; nn0 += 32) {
#pragma unroll
        for (int i = 0; i < 8; i++) {
            int idx = t + i * 256;
            int d = idx >> 5, c = idx & 31;
            ks[d][c] = bf2f(kb[base + (size_t)d * NPIX + nn0 + c]);
            vs[d][c] = bf2f(vb[base + (size_t)d * NPIX + nn0 + c]);
        }
        __syncthreads();
#pragma unroll 8
        for (int c = 0; c < 32; c++) {
            float a[4], bb[4];
#pragma unroll
            for (int i = 0; i < 4; i++) a[i] = ks[tr * 4 + i][c];
#pragma unroll
            for (int j = 0; j < 4; j++) bb[j] = vs[tc * 4 + j][c];
#pragma unroll
            for (int i = 0; i < 4; i++) {
                ksacc[i] += a[i];
#pragma unroll
                for (int j = 0; j < 4; j++)
                    acc[i][j] = fmaf(a[i], bb[j], acc[i][j]);
            }
        }
        __syncthreads();
    }

    float* kvb = kv + (size_t)(b * HEADS + h) * 64 * 64;
#pragma unroll
    for (int i = 0; i < 4; i++)
#pragma unroll
        for (int j = 0; j < 4; j++)
            atomicAdd(&kvb[(tr * 4 + i) * 64 + tc * 4 + j], acc[i][j]);
    if (tc == 0) {
        float* ksb = ksum + (b * HEADS + h) * 64;
#pragma unroll
        for (int i = 0; i < 4; i++) atomicAdd(&ksb[tr * 4 + i], ksacc[i]);
    }
}

// ---------------- K3: out = z * kv^T q ----------------
// grid (32 ntiles of 128 cols, 8 h, 8 b), block 256.
__global__ __launch_bounds__(256) void k_out(
    const unsigned short* __restrict__ qb,
    const float* __restrict__ kv,
    const float* __restrict__ ksum,
    unsigned short* __restrict__ outb)   // B x 512 x 4096 (hid = h*64+e)
{
    const int b = blockIdx.z, h = blockIdx.y, nt = blockIdx.x;
    const int t = threadIdx.x;
    const int tr = t >> 4, tc = t & 15;   // e-group, n-group

    __shared__ float kvs[64][65];   // [d][e]
    __shared__ float qs[64][65];    // [d][n]
    __shared__ float kss[64];

    const float* kvb = kv + (size_t)(b * HEADS + h) * 4096;
#pragma unroll
    for (int i = 0; i < 16; i++) {
        int idx = t + i * 256;
        kvs[idx >> 6][idx & 63] = kvb[idx];
    }
    if (t < 64) kss[t] = ksum[(b * HEADS + h) * 64 + t];

    const size_t qbase = ((size_t)b * HIDC + h * 64) * NPIX;

    for (int c0 = nt * 128; c0 < nt * 128 + 128; c0 += 64) {
        __syncthreads();   // protects qs reuse + makes kvs/kss visible
#pragma unroll
        for (int i = 0; i < 16; i++) {
            int idx = t + i * 256;
            int d = idx >> 6, nn = idx & 63;
            qs[d][nn] = bf2f(qb[qbase + (size_t)d * NPIX + c0 + nn]);
        }
        __syncthreads();

        float acc[4][4] = {{0}};
        float den[4] = {0, 0, 0, 0};
#pragma unroll 8
        for (int d = 0; d < 64; d++) {
            float a[4], qq[4];
#pragma unroll
            for (int i = 0; i < 4; i++) a[i] = kvs[d][tr * 4 + i];
#pragma unroll
            for (int j = 0; j < 4; j++) qq[j] = qs[d][tc * 4 + j];
            float kd = kss[d];
#pragma unroll
            for (int j = 0; j < 4; j++) den[j] = fmaf(kd, qq[j], den[j]);
#pragma unroll
            for (int i = 0; i < 4; i++)
#pragma unroll
                for (int j = 0; j < 4; j++)
                    acc[i][j] = fmaf(a[i], qq[j], acc[i][j]);
        }

#pragma unroll
        for (int j = 0; j < 4; j++) {
            float z = 1.f / (den[j] + 1e-6f);
            int n = c0 + tc * 4 + j;
#pragma unroll
            for (int i = 0; i < 4; i++) {
                outb[((size_t)b * HIDC + h * 64 + tr * 4 + i) * NPIX + n] =
                    f2bf(acc[i][j] * z);
            }
        }
    }
}

// ---------------- K4: y = Wout @ out + bout ----------------
// grid (32, 2, 8), block 256. Same tiling as K1, B operand is bf16.
__global__ __launch_bounds__(256) void k_y(
    const float* __restrict__ W,            // 256 x 512
    const unsigned short* __restrict__ ob,  // B x 512 x 4096 bf16
    const float* __restrict__ bout,         // 256
    float* __restrict__ y)                  // B x 256 x 4096
{
    const int b  = blockIdx.z;
    const int m0 = blockIdx.y * 128;
    const int n0 = blockIdx.x * 128;
    const int t  = threadIdx.x;
    const int tr = t >> 4, tc = t & 15;

    __shared__ float As[16][132];
    __shared__ float Bs[16][128];

    const unsigned short* B = ob + (size_t)b * HIDC * NPIX;

    float acc[8][8];
#pragma unroll
    for (int i = 0; i < 8; i++)
#pragma unroll
        for (int j = 0; j < 8; j++) acc[i][j] = 0.f;

    for (int k0 = 0; k0 < HIDC; k0 += 16) {
#pragma unroll
        for (int i = 0; i < 2; i++) {
            int idx = t + i * 256;
            int m = idx >> 2;
            int kq = idx & 3;
            const float4 av = *(const float4*)(W + (size_t)(m0 + m) * HIDC + k0 + kq * 4);
            As[kq * 4 + 0][m] = av.x;
            As[kq * 4 + 1][m] = av.y;
            As[kq * 4 + 2][m] = av.z;
            As[kq * 4 + 3][m] = av.w;
        }
#pragma unroll
        for (int i = 0; i < 2; i++) {
            int idx = t + i * 256;
            int kk = idx >> 5;
            int n4 = idx & 31;
            const ushort4 hv = *(const ushort4*)(B + (size_t)(k0 + kk) * NPIX + n0 + n4 * 4);
            Bs[kk][n4 * 4 + 0] = bf2f(hv.x);
            Bs[kk][n4 * 4 + 1] = bf2f(hv.y);
            Bs[kk][n4 * 4 + 2] = bf2f(hv.z);
            Bs[kk][n4 * 4 + 3] = bf2f(hv.w);
        }
        __syncthreads();
#pragma unroll
        for (int kk = 0; kk < 16; kk++) {
            float a[8], bb[8];
            *(float4*)(a)     = *(const float4*)(&As[kk][tr * 8]);
            *(float4*)(a + 4) = *(const float4*)(&As[kk][tr * 8 + 4]);
            *(float4*)(bb)     = *(const float4*)(&Bs[kk][tc * 8]);
            *(float4*)(bb + 4) = *(const float4*)(&Bs[kk][tc * 8 + 4]);
#pragma unroll
            for (int i = 0; i < 8; i++)
#pragma unroll
                for (int j = 0; j < 8; j++)
                    acc[i][j] = fmaf(a[i], bb[j], acc[i][j]);
        }
        __syncthreads();
    }

#pragma unroll
    for (int i = 0; i < 8; i++) {
        int row = m0 + tr * 8 + i;
        float bias = bout[row];
        float vals[8];
#pragma unroll
        for (int j = 0; j < 8; j++) vals[j] = acc[i][j] + bias;
        float* dst = y + ((size_t)b * DIMC + row) * NPIX + n0 + tc * 8;
        *(float4*)(dst)     = *(const float4*)(vals);
        *(float4*)(dst + 4) = *(const float4*)(vals + 4);
    }
}

extern "C" void kernel_launch(void* const* d_in, const int* in_sizes, int n_in,
                              void* d_out, int out_size, void* d_ws, size_t ws_size,
                              hipStream_t stream) {
    const float* x    = (const float*)d_in[0];
    const float* cm   = (const float*)d_in[1];
    const float* Wqkv = (const float*)d_in[2];
    const float* Wout = (const float*)d_in[3];
    const float* bout = (const float*)d_in[4];
    const float* csp  = (const float*)d_in[5];
    float* y = (float*)d_out;

    const size_t qn = (size_t)BATCH * HIDC * NPIX;   // 16,777,216 elems
    unsigned short* qb = (unsigned short*)d_ws;
    unsigned short* kb = qb + qn;
    unsigned short* vb = kb + qn;
    unsigned short* ob = vb + qn;
    float* kv   = (float*)(ob + qn);
    float* ksum = kv + (size_t)BATCH * HEADS * 64 * 64;

    // zero the atomic accumulators (ws is re-poisoned before every launch)
    hipMemsetAsync(kv, 0,
                   ((size_t)BATCH * HEADS * 64 * 64 + BATCH * HEADS * 64) * sizeof(float),
                   stream);

    k_qkv<<<dim3(32, 12, 8), 256, 0, stream>>>(Wqkv, x, cm, csp, qb, kb, vb);
    k_kv <<<dim3(8, 8, 8),   256, 0, stream>>>(kb, vb, kv, ksum);
    k_out<<<dim3(32, 8, 8),  256, 0, stream>>>(qb, kv, ksum, ob);
    k_y  <<<dim3(32, 2, 8),  256, 0, stream>>>(Wout, ob, bout, y);
}

// Round 2
// 223.227 us; speedup vs baseline: 2.6855x; 2.6855x over previous
//
#include <hip/hip_runtime.h>
#include <stdint.h>

// LinearAttention MI355X round 2: all GEMM-shaped stages on bf16 MFMA (16x16x32).
// B=8, DIM=256, HEADS=8, DHEAD=64, HID=512, NPIX=4096.
// K0a: Wqkv/Wout fp32 -> bf16 (row-major, k contiguous)
// K0b: x [b][c][n] fp32 -> xT [b][n][c] bf16 (LDS-tiled transpose)
// K1:  qkv^T = xT @ Wb^T, fused elu1/contact-gate; q -> qT[b][n][512], k,v -> [b][512][n]
// K2:  kv[bh][d][e] = sum_n k*v (MFMA over n, split-8 + atomics), ksum fused
// K3:  outT[b][n][512] = z * (kv^T q); den via extra MFMA n-tile (ksum hi+lo bf16)
// K4:  y = outT @ Wob^T + bout -> fp32 [b][256][4096]

#define NPIX 4096
#define HIDC 512
#define DIMC 256
#define BATCH 8

typedef __attribute__((ext_vector_type(8))) short bf16x8;
typedef __attribute__((ext_vector_type(4))) float f32x4;

__device__ __forceinline__ float bf2f(unsigned short h) {
    unsigned int u = ((unsigned int)h) << 16; float f;
    __builtin_memcpy(&f, &u, 4); return f;
}
__device__ __forceinline__ unsigned short f2bf(float f) {
    unsigned int u; __builtin_memcpy(&u, &f, 4);
    u += 0x7fffu + ((u >> 16) & 1u);
    return (unsigned short)(u >> 16);
}
__device__ __forceinline__ float elu1(float x) {
    return x > 0.f ? x + 1.f : __expf(x);
}

// ---------------- K0a: weight conversion ----------------
__global__ __launch_bounds__(256) void k_convW(
    const float* __restrict__ Wqkv, const float* __restrict__ Wout,
    unsigned short* __restrict__ Wb, unsigned short* __restrict__ Wob)
{
    int i4 = (blockIdx.x * 256 + threadIdx.x) * 4;
    const int NW1 = 1536 * 256;
    float4 v; unsigned short* dst;
    if (i4 < NW1) { v = *(const float4*)&Wqkv[i4]; dst = Wb + i4; }
    else { int j = i4 - NW1; v = *(const float4*)&Wout[j]; dst = Wob + j; }
    ushort4 o; o.x = f2bf(v.x); o.y = f2bf(v.y); o.z = f2bf(v.z); o.w = f2bf(v.w);
    *(ushort4*)dst = o;
}

// ---------------- K0b: x transpose+convert ----------------
// grid (128 n-tiles, 8 c-tiles, 8 b), block 256
__global__ __launch_bounds__(256) void k_tx(
    const float* __restrict__ x, unsigned short* __restrict__ xT)
{
    __shared__ float tile[32][33];
    const int n0 = blockIdx.x * 32, c0 = blockIdx.y * 32, b = blockIdx.z;
    const int t = threadIdx.x;
    const int r = t >> 3, c4 = (t & 7) * 4;
    float4 v = *(const float4*)&x[((size_t)b * DIMC + c0 + r) * NPIX + n0 + c4];
    tile[r][c4 + 0] = v.x; tile[r][c4 + 1] = v.y;
    tile[r][c4 + 2] = v.z; tile[r][c4 + 3] = v.w;
    __syncthreads();
    ushort4 o;
    unsigned short* op = (unsigned short*)&o;
#pragma unroll
    for (int i = 0; i < 4; i++) op[i] = f2bf(tile[c4 + i][r]);
    *(ushort4*)&xT[((size_t)b * NPIX + n0 + r) * DIMC + c0 + c4] = o;
}

// ---------------- K1: qkv MFMA GEMM ----------------
// D[m=pixel][n=o], M=4096, N=1536, K=256. grid (32, 12, 8), block 256 (4 waves 2x2).
__global__ __launch_bounds__(256) void k_qkv(
    const unsigned short* __restrict__ xT,   // B x 4096 x 256
    const unsigned short* __restrict__ Wb,   // 1536 x 256
    const float* __restrict__ cmp,           // B x 4096
    const float* __restrict__ csp,
    unsigned short* __restrict__ qT,         // B x 4096 x 512
    unsigned short* __restrict__ kb,         // B x 512 x 4096
    unsigned short* __restrict__ vb)         // B x 512 x 4096
{
    const int b  = blockIdx.z;
    const int m0 = blockIdx.x * 128;
    const int n0 = blockIdx.y * 128;
    const int t = threadIdx.x;
    const int wave = t >> 6, lane = t & 63;
    const int wm = wave >> 1, wn = wave & 1;
    const int lrow = lane & 15, quad = lane >> 4;

    __shared__ unsigned short As[128 * 32];
    __shared__ unsigned short Bs[128 * 32];

    const unsigned short* Ag = xT + ((size_t)b * NPIX + m0) * DIMC;
    const unsigned short* Bg = Wb + (size_t)n0 * DIMC;

    f32x4 acc[4][4];
#pragma unroll
    for (int i = 0; i < 4; i++)
#pragma unroll
        for (int j = 0; j < 4; j++) acc[i][j] = (f32x4){0.f, 0.f, 0.f, 0.f};

    for (int k0 = 0; k0 < DIMC; k0 += 32) {
#pragma unroll
        for (int i = 0; i < 2; i++) {
            int chunk = t + i * 256;
            int row = chunk >> 2, c8 = (chunk & 3) * 8;
            *(uint4*)&As[row * 32 + c8] = *(const uint4*)&Ag[(size_t)row * DIMC + k0 + c8];
            *(uint4*)&Bs[row * 32 + c8] = *(const uint4*)&Bg[(size_t)row * DIMC + k0 + c8];
        }
        __syncthreads();
        bf16x8 af[4], bfr[4];
#pragma unroll
        for (int mt = 0; mt < 4; mt++)
            af[mt] = *(const bf16x8*)&As[(wm * 64 + mt * 16 + lrow) * 32 + quad * 8];
#pragma unroll
        for (int nt = 0; nt < 4; nt++)
            bfr[nt] = *(const bf16x8*)&Bs[(wn * 64 + nt * 16 + lrow) * 32 + quad * 8];
#pragma unroll
        for (int mt = 0; mt < 4; mt++)
#pragma unroll
            for (int nt = 0; nt < 4; nt++)
                acc[mt][nt] = __builtin_amdgcn_mfma_f32_16x16x32_bf16(
                    af[mt], bfr[nt], acc[mt][nt], 0, 0, 0);
        __syncthreads();
    }

    const int sect = n0 >> 9;          // 0=q, 1=k, 2=v (uniform per block)
    const float cs = *csp;

#pragma unroll
    for (int mt = 0; mt < 4; mt++) {
        const int pixel0 = m0 + wm * 64 + mt * 16 + quad * 4;
        float4 cmv;
        if (sect == 1) cmv = *(const float4*)&cmp[(size_t)b * NPIX + pixel0];
        const float* cm4 = (const float*)&cmv;
#pragma unroll
        for (int nt = 0; nt < 4; nt++) {
            const int o = n0 + wn * 64 + nt * 16 + lrow;
            f32x4 a = acc[mt][nt];
            if (sect == 0) {
#pragma unroll
                for (int r = 0; r < 4; r++)
                    qT[((size_t)b * NPIX + pixel0 + r) * HIDC + o] = f2bf(elu1(a[r]));
            } else if (sect == 1) {
                ushort4 st; unsigned short* sp = (unsigned short*)&st;
#pragma unroll
                for (int r = 0; r < 4; r++)
                    sp[r] = f2bf(elu1(a[r]) * (1.f + cs * cm4[r]));
                *(ushort4*)&kb[((size_t)b * HIDC + (o - 512)) * NPIX + pixel0] = st;
            } else {
                ushort4 st; unsigned short* sp = (unsigned short*)&st;
#pragma unroll
                for (int r = 0; r < 4; r++) sp[r] = f2bf(a[r]);
                *(ushort4*)&vb[((size_t)b * HIDC + (o - 1024)) * NPIX + pixel0] = st;
            }
        }
    }
}

// ---------------- K2: kv + ksum (MFMA over n) ----------------
// grid (8 n-chunks, 64 bh), block 256. D[m=d][n=e] 64x64, K-chunk 512.
__global__ __launch_bounds__(256) void k_kv(
    const unsigned short* __restrict__ kb, const unsigned short* __restrict__ vb,
    float* __restrict__ kv, float* __restrict__ ksum)
{
    const int bh = blockIdx.y, nc = blockIdx.x;
    const int t = threadIdx.x, wave = t >> 6, lane = t & 63;
    const int lrow = lane & 15, quad = lane >> 4;

    __shared__ unsigned short ks[64 * 32];
    __shared__ unsigned short vs[64 * 32];

    const size_t base = (size_t)bh * 64 * NPIX;
    f32x4 acc[4];
#pragma unroll
    for (int i = 0; i < 4; i++) acc[i] = (f32x4){0.f, 0.f, 0.f, 0.f};
    float ksacc = 0.f;

    const int row = t >> 2, c8 = (t & 3) * 8;

    for (int step = 0; step < 16; step++) {
        const int ncol = nc * 512 + step * 32;
        uint4 kq = *(const uint4*)&kb[base + (size_t)row * NPIX + ncol + c8];
        *(uint4*)&ks[row * 32 + c8] = kq;
        *(uint4*)&vs[row * 32 + c8] = *(const uint4*)&vb[base + (size_t)row * NPIX + ncol + c8];
        const unsigned short* kp = (const unsigned short*)&kq;
#pragma unroll
        for (int j = 0; j < 8; j++) ksacc += bf2f(kp[j]);
        __syncthreads();
        bf16x8 bfv = *(const bf16x8*)&vs[(wave * 16 + lrow) * 32 + quad * 8];
#pragma unroll
        for (int mt = 0; mt < 4; mt++) {
            bf16x8 af = *(const bf16x8*)&ks[(mt * 16 + lrow) * 32 + quad * 8];
            acc[mt] = __builtin_amdgcn_mfma_f32_16x16x32_bf16(af, bfv, acc[mt], 0, 0, 0);
        }
        __syncthreads();
    }

    float* kvb = kv + (size_t)bh * 4096;
#pragma unroll
    for (int mt = 0; mt < 4; mt++)
#pragma unroll
        for (int r = 0; r < 4; r++)
            atomicAdd(&kvb[(mt * 16 + quad * 4 + r) * 64 + wave * 16 + lrow], acc[mt][r]);
    atomicAdd(&ksum[bh * 64 + row], ksacc);
}

// ---------------- K3: out = z * kv^T q  (MFMA, K=d=64) ----------------
// grid (32 pixel-tiles, 64 bh), block 256. D[m=pixel 128][n=e 64 + den-tile].
__global__ __launch_bounds__(256) void k_out(
    const unsigned short* __restrict__ qT,   // B x 4096 x 512
    const float* __restrict__ kv, const float* __restrict__ ksum,
    unsigned short* __restrict__ outT)       // B x 4096 x 512
{
    const int bh = blockIdx.y, p0 = blockIdx.x * 128;
    const int b = bh >> 3, h = bh & 7;
    const int t = threadIdx.x, wave = t >> 6, lane = t & 63;
    const int lrow = lane & 15, quad = lane >> 4;

    __shared__ unsigned short Aq[128 * 64];  // [pixel][d]
    __shared__ unsigned short Bv[80 * 64];   // [n][d]: 0..63 kvT, 64 ksum_hi, 65 ksum_lo

    const unsigned short* qg = qT + ((size_t)b * NPIX + p0) * HIDC + h * 64;
#pragma unroll
    for (int i = 0; i < 4; i++) {
        int chunk = t + i * 256;
        int row = chunk >> 3, c8 = (chunk & 7) * 8;
        *(uint4*)&Aq[row * 64 + c8] = *(const uint4*)&qg[(size_t)row * HIDC + c8];
    }
    const float* kvg = kv + (size_t)bh * 4096;
#pragma unroll
    for (int i = 0; i < 16; i++) {
        int idx = t + i * 256;
        int e = idx >> 6, d = idx & 63;
        Bv[e * 64 + d] = f2bf(kvg[(size_t)d * 64 + e]);
    }
    if (t < 64) {
        float ksv = ksum[bh * 64 + t];
        unsigned short hi = f2bf(ksv);
        Bv[64 * 64 + t] = hi;
        Bv[65 * 64 + t] = f2bf(ksv - bf2f(hi));
#pragma unroll
        for (int rr = 66; rr < 80; rr++) Bv[rr * 64 + t] = 0;
    }
    __syncthreads();

    f32x4 acc[2][5];
#pragma unroll
    for (int i = 0; i < 2; i++)
#pragma unroll
        for (int j = 0; j < 5; j++) acc[i][j] = (f32x4){0.f, 0.f, 0.f, 0.f};

#pragma unroll
    for (int ksp = 0; ksp < 2; ksp++) {
        bf16x8 af[2], bfr[5];
#pragma unroll
        for (int mt = 0; mt < 2; mt++)
            af[mt] = *(const bf16x8*)&Aq[(wave * 32 + mt * 16 + lrow) * 64 + ksp * 32 + quad * 8];
#pragma unroll
        for (int nt = 0; nt < 5; nt++)
            bfr[nt] = *(const bf16x8*)&Bv[(nt * 16 + lrow) * 64 + ksp * 32 + quad * 8];
#pragma unroll
        for (int mt = 0; mt < 2; mt++)
#pragma unroll
            for (int nt = 0; nt < 5; nt++)
                acc[mt][nt] = __builtin_amdgcn_mfma_f32_16x16x32_bf16(
                    af[mt], bfr[nt], acc[mt][nt], 0, 0, 0);
    }

    unsigned short* og = outT + ((size_t)b * NPIX + p0) * HIDC + h * 64;
#pragma unroll
    for (int mt = 0; mt < 2; mt++) {
        const int prow = wave * 32 + mt * 16 + quad * 4;
        float z[4];
#pragma unroll
        for (int r = 0; r < 4; r++) {
            float hi = __shfl(acc[mt][4][r], lane & 48);
            float lo = __shfl(acc[mt][4][r], (lane & 48) | 1);
            z[r] = 1.f / (hi + lo + 1e-6f);
        }
#pragma unroll
        for (int nt = 0; nt < 4; nt++)
#pragma unroll
            for (int r = 0; r < 4; r++)
                og[(size_t)(prow + r) * HIDC + nt * 16 + lrow] = f2bf(acc[mt][nt][r] * z[r]);
    }
}

// ---------------- K4: y = outT @ Wob^T + bout ----------------
// D[m=pixel][n=o], M=4096, N=256, K=512. grid (32, 2, 8), block 256.
__global__ __launch_bounds__(256) void k_y(
    const unsigned short* __restrict__ outT,  // B x 4096 x 512
    const unsigned short* __restrict__ Wob,   // 256 x 512
    const float* __restrict__ bout,
    float* __restrict__ y)                    // B x 256 x 4096
{
    const int b  = blockIdx.z;
    const int m0 = blockIdx.x * 128;
    const int n0 = blockIdx.y * 128;
    const int t = threadIdx.x;
    const int wave = t >> 6, lane = t & 63;
    const int wm = wave >> 1, wn = wave & 1;
    const int lrow = lane & 15, quad = lane >> 4;

    __shared__ unsigned short As[128 * 32];
    __shared__ unsigned short Bs[128 * 32];

    const unsigned short* Ag = outT + ((size_t)b * NPIX + m0) * HIDC;
    const unsigned short* Bg = Wob + (size_t)n0 * HIDC;

    f32x4 acc[4][4];
#pragma unroll
    for (int i = 0; i < 4; i++)
#pragma unroll
        for (int j = 0; j < 4; j++) acc[i][j] = (f32x4){0.f, 0.f, 0.f, 0.f};

    for (int k0 = 0; k0 < HIDC; k0 += 32) {
#pragma unroll
        for (int i = 0; i < 2; i++) {
            int chunk = t + i * 256;
            int row = chunk >> 2, c8 = (chunk & 3) * 8;
            *(uint4*)&As[row * 32 + c8] = *(const uint4*)&Ag[(size_t)row * HIDC + k0 + c8];
            *(uint4*)&Bs[row * 32 + c8] = *(const uint4*)&Bg[(size_t)row * HIDC + k0 + c8];
        }
        __syncthreads();
        bf16x8 af[4], bfr[4];
#pragma unroll
        for (int mt = 0; mt < 4; mt++)
            af[mt] = *(const bf16x8*)&As[(wm * 64 + mt * 16 + lrow) * 32 + quad * 8];
#pragma unroll
        for (int nt = 0; nt < 4; nt++)
            bfr[nt] = *(const bf16x8*)&Bs[(wn * 64 + nt * 16 + lrow) * 32 + quad * 8];
#pragma unroll
        for (int mt = 0; mt < 4; mt++)
#pragma unroll
            for (int nt = 0; nt < 4; nt++)
                acc[mt][nt] = __builtin_amdgcn_mfma_f32_16x16x32_bf16(
                    af[mt], bfr[nt], acc[mt][nt], 0, 0, 0);
        __syncthreads();
    }

#pragma unroll
    for (int mt = 0; mt < 4; mt++) {
        const int pixel0 = m0 + wm * 64 + mt * 16 + quad * 4;
#pragma unroll
        for (int nt = 0; nt < 4; nt++) {
            const int o = n0 + wn * 64 + nt * 16 + lrow;
            const float bias = bout[o];
            f32x4 a = acc[mt][nt];
            float4 st; st.x = a[0] + bias; st.y = a[1] + bias;
            st.z = a[2] + bias; st.w = a[3] + bias;
            *(float4*)&y[((size_t)b * DIMC + o) * NPIX + pixel0] = st;
        }
    }
}

extern "C" void kernel_launch(void* const* d_in, const int* in_sizes, int n_in,
                              void* d_out, int out_size, void* d_ws, size_t ws_size,
                              hipStream_t stream) {
    (void)in_sizes; (void)n_in; (void)out_size; (void)ws_size;
    const float* x    = (const float*)d_in[0];
    const float* cm   = (const float*)d_in[1];
    const float* Wqkv = (const float*)d_in[2];
    const float* Wout = (const float*)d_in[3];
    const float* bout = (const float*)d_in[4];
    const float* csp  = (const float*)d_in[5];
    float* y = (float*)d_out;

    const size_t qn = (size_t)BATCH * HIDC * NPIX;   // 16,777,216 bf16 elems
    char* ws = (char*)d_ws;
    unsigned short* qT   = (unsigned short*)ws;                 ws += qn * 2;
    unsigned short* kb   = (unsigned short*)ws;                 ws += qn * 2;
    unsigned short* vb   = (unsigned short*)ws;                 ws += qn * 2;
    unsigned short* outT = (unsigned short*)ws;                 ws += qn * 2;
    unsigned short* xT   = outT;  // alias: xT (16.8MB) dead before outT written
    // wait: xT must NOT alias outT's live range... K3 writes outT, K1 reads xT.
    // K1 finishes before K3 starts (stream-ordered) -> safe.
    float* kvp   = (float*)ws;                                  ws += (size_t)64 * 64 * 64 * 4;
    float* ksump = (float*)ws;                                  ws += (size_t)64 * 64 * 4;
    unsigned short* Wb  = (unsigned short*)ws;                  ws += (size_t)1536 * 256 * 2;
    unsigned short* Wob = (unsigned short*)ws;

    hipMemsetAsync(kvp, 0, ((size_t)64 * 64 * 64 + 64 * 64) * sizeof(float), stream);
    k_convW<<<512, 256, 0, stream>>>(Wqkv, Wout, Wb, Wob);
    k_tx  <<<dim3(128, 8, 8), 256, 0, stream>>>(x, xT);
    k_qkv <<<dim3(32, 12, 8), 256, 0, stream>>>(xT, Wb, cm, csp, qT, kb, vb);
    k_kv  <<<dim3(8, 64),     256, 0, stream>>>(kb, vb, kvp, ksump);
    k_out <<<dim3(32, 64),    256, 0, stream>>>(qT, kvp, ksump, outT);
    k_y   <<<dim3(32, 2, 8),  256, 0, stream>>>(outT, Wob, bout, y);
}

// Round 3
// 214.775 us; speedup vs baseline: 2.7911x; 1.0394x over previous
//
#include <hip/hip_runtime.h>
#include <stdint.h>

// LinearAttention MI355X round 3: 32x32x16 MFMA frags for full-sector (64B) stores,
// per-section operand swap in K1, padded LDS strides everywhere.
// B=8, DIM=256, HEADS=8, DHEAD=64, HID=512, NPIX=4096.

#define NPIX 4096
#define HIDC 512
#define DIMC 256
#define BATCH 8

typedef __attribute__((ext_vector_type(8))) short bf16x8;
typedef __attribute__((ext_vector_type(4))) float f32x4;
typedef __attribute__((ext_vector_type(16))) float f32x16;

__device__ __forceinline__ float bf2f(unsigned short h) {
    unsigned int u = ((unsigned int)h) << 16; float f;
    __builtin_memcpy(&f, &u, 4); return f;
}
__device__ __forceinline__ unsigned short f2bf(float f) {
    unsigned int u; __builtin_memcpy(&u, &f, 4);
    u += 0x7fffu + ((u >> 16) & 1u);
    return (unsigned short)(u >> 16);
}
__device__ __forceinline__ float elu1(float x) {
    return x > 0.f ? x + 1.f : __expf(x);
}

// ---------------- K0a: weight conversion ----------------
__global__ __launch_bounds__(256) void k_convW(
    const float* __restrict__ Wqkv, const float* __restrict__ Wout,
    unsigned short* __restrict__ Wb, unsigned short* __restrict__ Wob)
{
    int i4 = (blockIdx.x * 256 + threadIdx.x) * 4;
    const int NW1 = 1536 * 256;
    float4 v; unsigned short* dst;
    if (i4 < NW1) { v = *(const float4*)&Wqkv[i4]; dst = Wb + i4; }
    else { int j = i4 - NW1; v = *(const float4*)&Wout[j]; dst = Wob + j; }
    ushort4 o; o.x = f2bf(v.x); o.y = f2bf(v.y); o.z = f2bf(v.z); o.w = f2bf(v.w);
    *(ushort4*)dst = o;
}

// ---------------- K0b: x transpose+convert ----------------
__global__ __launch_bounds__(256) void k_tx(
    const float* __restrict__ x, unsigned short* __restrict__ xT)
{
    __shared__ float tile[32][33];
    const int n0 = blockIdx.x * 32, c0 = blockIdx.y * 32, b = blockIdx.z;
    const int t = threadIdx.x;
    const int r = t >> 3, c4 = (t & 7) * 4;
    float4 v = *(const float4*)&x[((size_t)b * DIMC + c0 + r) * NPIX + n0 + c4];
    tile[r][c4 + 0] = v.x; tile[r][c4 + 1] = v.y;
    tile[r][c4 + 2] = v.z; tile[r][c4 + 3] = v.w;
    __syncthreads();
    ushort4 o;
    unsigned short* op = (unsigned short*)&o;
#pragma unroll
    for (int i = 0; i < 4; i++) op[i] = f2bf(tile[c4 + i][r]);
    *(ushort4*)&xT[((size_t)b * NPIX + n0 + r) * DIMC + c0 + c4] = o;
}

// ---------------- K1: qkv MFMA GEMM (32x32x16, operand swap per section) ----
// grid (32 pixel-tiles, 12 o-tiles, 8 b), block 256 (4 waves, 2x2 of 64x64).
#define LS1 40   // LDS row stride (ushorts), 80B, 16B-aligned, breaks bank aliasing
__global__ __launch_bounds__(256) void k_qkv(
    const unsigned short* __restrict__ xT,   // B x 4096 x 256
    const unsigned short* __restrict__ Wb,   // 1536 x 256
    const float* __restrict__ cmp,           // B x 4096
    const float* __restrict__ csp,
    unsigned short* __restrict__ qT,         // B x 4096 x 512 (pixel-major)
    unsigned short* __restrict__ kb,         // B x 512 x 4096 (channel-major)
    unsigned short* __restrict__ vb)         // B x 512 x 4096
{
    const int b  = blockIdx.z;
    const int m0 = blockIdx.x * 128;   // pixel tile
    const int n0 = blockIdx.y * 128;   // o tile
    const int t = threadIdx.x;
    const int wave = t >> 6, lane = t & 63;
    const int wm = wave >> 1, wn = wave & 1;
    const int l31 = lane & 31, lhi = lane >> 5;
    const int sect = n0 >> 9;          // 0=q, 1=k, 2=v (block-uniform)

    __shared__ unsigned short As[128 * LS1];  // xT tile  [pixel][32k]
    __shared__ unsigned short Bs[128 * LS1];  // W tile   [o][32k]

    const unsigned short* Ag = xT + ((size_t)b * NPIX + m0) * DIMC;
    const unsigned short* Bg = Wb + (size_t)n0 * DIMC;

    // operand roles: sect==0 -> m=pixel(A=xT), col=o ; else m=o(A=W), col=pixel
    const unsigned short* mArr = (sect == 0) ? As : Bs;
    const unsigned short* nArr = (sect == 0) ? Bs : As;

    f32x16 acc[2][2];
#pragma unroll
    for (int i = 0; i < 2; i++)
#pragma unroll
        for (int j = 0; j < 2; j++)
#pragma unroll
            for (int r = 0; r < 16; r++) acc[i][j][r] = 0.f;

    const int srow = t >> 2, sc8 = (t & 3) * 8;
    for (int k0 = 0; k0 < DIMC; k0 += 32) {
        *(uint4*)&As[srow * LS1 + sc8] =
            *(const uint4*)&Ag[(size_t)srow * DIMC + k0 + sc8];
        *(uint4*)&As[(srow + 64) * LS1 + sc8] =
            *(const uint4*)&Ag[(size_t)(srow + 64) * DIMC + k0 + sc8];
        *(uint4*)&Bs[srow * LS1 + sc8] =
            *(const uint4*)&Bg[(size_t)srow * DIMC + k0 + sc8];
        *(uint4*)&Bs[(srow + 64) * LS1 + sc8] =
            *(const uint4*)&Bg[(size_t)(srow + 64) * DIMC + k0 + sc8];
        __syncthreads();
#pragma unroll
        for (int ks = 0; ks < 2; ks++) {
            bf16x8 af[2], bfg[2];
#pragma unroll
            for (int fm = 0; fm < 2; fm++)
                af[fm] = *(const bf16x8*)&mArr[(wm * 64 + fm * 32 + l31) * LS1 + ks * 16 + lhi * 8];
#pragma unroll
            for (int fn = 0; fn < 2; fn++)
                bfg[fn] = *(const bf16x8*)&nArr[(wn * 64 + fn * 32 + l31) * LS1 + ks * 16 + lhi * 8];
#pragma unroll
            for (int fm = 0; fm < 2; fm++)
#pragma unroll
                for (int fn = 0; fn < 2; fn++)
                    acc[fm][fn] = __builtin_amdgcn_mfma_f32_32x32x16_bf16(
                        af[fm], bfg[fn], acc[fm][fn], 0, 0, 0);
        }
        __syncthreads();
    }

    const float cs = *csp;
    if (sect == 0) {
        // C: row=pixel, col=o. Store pixel-major: 64B runs per instr.
#pragma unroll
        for (int fm = 0; fm < 2; fm++) {
            const int pbase = m0 + wm * 64 + fm * 32;
#pragma unroll
            for (int fn = 0; fn < 2; fn++) {
                const int o = n0 + wn * 64 + fn * 32 + l31;
#pragma unroll
                for (int r = 0; r < 16; r++) {
                    int prow = pbase + (r & 3) + 8 * (r >> 2) + 4 * lhi;
                    qT[((size_t)b * NPIX + prow) * HIDC + o] = f2bf(elu1(acc[fm][fn][r]));
                }
            }
        }
    } else {
        // C: row=o, col=pixel. Store channel-major: 64B runs per instr.
        unsigned short* dstb = (sect == 1) ? kb : vb;
#pragma unroll
        for (int fm = 0; fm < 2; fm++) {
            const int obase = (n0 & 511) + wm * 64 + fm * 32;
#pragma unroll
            for (int fn = 0; fn < 2; fn++) {
                const int pixel = m0 + wn * 64 + fn * 32 + l31;
                float g = 1.f;
                if (sect == 1) g = 1.f + cs * cmp[(size_t)b * NPIX + pixel];
#pragma unroll
                for (int r = 0; r < 16; r++) {
                    int orow = obase + (r & 3) + 8 * (r >> 2) + 4 * lhi;
                    float val = acc[fm][fn][r];
                    if (sect == 1) val = elu1(val) * g;
                    dstb[((size_t)b * HIDC + orow) * NPIX + pixel] = f2bf(val);
                }
            }
        }
    }
}

// ---------------- K2: kv + ksum (MFMA over n), channel-major k/v ----------
#define LS2 40
__global__ __launch_bounds__(256) void k_kv(
    const unsigned short* __restrict__ kb, const unsigned short* __restrict__ vb,
    float* __restrict__ kv, float* __restrict__ ksum)
{
    const int bh = blockIdx.y, nc = blockIdx.x;
    const int t = threadIdx.x, wave = t >> 6, lane = t & 63;
    const int lrow = lane & 15, quad = lane >> 4;

    __shared__ unsigned short ks[64 * LS2];
    __shared__ unsigned short vs[64 * LS2];

    const size_t base = (size_t)bh * 64 * NPIX;
    f32x4 acc[4];
#pragma unroll
    for (int i = 0; i < 4; i++) acc[i] = (f32x4){0.f, 0.f, 0.f, 0.f};
    float ksacc = 0.f;

    const int row = t >> 2, c8 = (t & 3) * 8;

    for (int step = 0; step < 16; step++) {
        const int ncol = nc * 512 + step * 32;
        uint4 kq = *(const uint4*)&kb[base + (size_t)row * NPIX + ncol + c8];
        *(uint4*)&ks[row * LS2 + c8] = kq;
        *(uint4*)&vs[row * LS2 + c8] = *(const uint4*)&vb[base + (size_t)row * NPIX + ncol + c8];
        const unsigned short* kp = (const unsigned short*)&kq;
#pragma unroll
        for (int j = 0; j < 8; j++) ksacc += bf2f(kp[j]);
        __syncthreads();
        bf16x8 bfv = *(const bf16x8*)&vs[(wave * 16 + lrow) * LS2 + quad * 8];
#pragma unroll
        for (int mt = 0; mt < 4; mt++) {
            bf16x8 af = *(const bf16x8*)&ks[(mt * 16 + lrow) * LS2 + quad * 8];
            acc[mt] = __builtin_amdgcn_mfma_f32_16x16x32_bf16(af, bfv, acc[mt], 0, 0, 0);
        }
        __syncthreads();
    }

    float* kvb = kv + (size_t)bh * 4096;
#pragma unroll
    for (int mt = 0; mt < 4; mt++)
#pragma unroll
        for (int r = 0; r < 4; r++)
            atomicAdd(&kvb[(mt * 16 + quad * 4 + r) * 64 + wave * 16 + lrow], acc[mt][r]);
    atomicAdd(&ksum[bh * 64 + row], ksacc);
}

// ---------------- K3: out = z * kv^T q  (32x32x16, K=d=64) ----------------
// grid (32 pixel-tiles, 64 bh), block 256.
#define LS3 72   // 144B rows, 16B-aligned
__global__ __launch_bounds__(256) void k_out(
    const unsigned short* __restrict__ qT,   // B x 4096 x 512
    const float* __restrict__ kv, const float* __restrict__ ksum,
    unsigned short* __restrict__ outT)       // B x 4096 x 512
{
    const int bh = blockIdx.y, p0 = blockIdx.x * 128;
    const int b = bh >> 3, h = bh & 7;
    const int t = threadIdx.x, wave = t >> 6, lane = t & 63;
    const int l31 = lane & 31, lhi = lane >> 5;

    __shared__ unsigned short Aq[128 * LS3];  // [pixel][d]
    __shared__ unsigned short Bv[96 * LS3];   // [n][d]: 0..63 kvT, 64 hi, 65 lo, 66..95 zero

    const unsigned short* qg = qT + ((size_t)b * NPIX + p0) * HIDC + h * 64;
#pragma unroll
    for (int i = 0; i < 4; i++) {
        int idx = t + i * 256;
        int row = idx >> 3, c8 = (idx & 7) * 8;
        *(uint4*)&Aq[row * LS3 + c8] = *(const uint4*)&qg[(size_t)row * HIDC + c8];
    }
    const float* kvg = kv + (size_t)bh * 4096;
#pragma unroll
    for (int i = 0; i < 16; i++) {
        int idx = t + i * 256;          // coalesced read, transposed LDS write
        int d = idx >> 6, e = idx & 63;
        Bv[e * LS3 + d] = f2bf(kvg[idx]);
    }
    if (t < 64) {
        float ksv = ksum[bh * 64 + t];
        unsigned short hi = f2bf(ksv);
        Bv[64 * LS3 + t] = hi;
        Bv[65 * LS3 + t] = f2bf(ksv - bf2f(hi));
    }
    for (int i = t; i < 30 * 64; i += 256)
        Bv[(66 + (i >> 6)) * LS3 + (i & 63)] = 0;
    __syncthreads();

    f32x16 acc[3];
#pragma unroll
    for (int j = 0; j < 3; j++)
#pragma unroll
        for (int r = 0; r < 16; r++) acc[j][r] = 0.f;

#pragma unroll
    for (int ksub = 0; ksub < 4; ksub++) {
        const int koff = ksub * 16 + lhi * 8;
        bf16x8 af = *(const bf16x8*)&Aq[(wave * 32 + l31) * LS3 + koff];
#pragma unroll
        for (int nf = 0; nf < 3; nf++) {
            bf16x8 bfg = *(const bf16x8*)&Bv[(nf * 32 + l31) * LS3 + koff];
            acc[nf] = __builtin_amdgcn_mfma_f32_32x32x16_bf16(af, bfg, acc[nf], 0, 0, 0);
        }
    }

    unsigned short* og = outT + ((size_t)b * NPIX + p0 + wave * 32) * HIDC + h * 64;
#pragma unroll
    for (int r = 0; r < 16; r++) {
        float hi = __shfl(acc[2][r], lane & 32);
        float lo = __shfl(acc[2][r], (lane & 32) | 1);
        float z = 1.f / (hi + lo + 1e-6f);
        int prow = (r & 3) + 8 * (r >> 2) + 4 * lhi;
#pragma unroll
        for (int nf = 0; nf < 2; nf++)
            og[(size_t)prow * HIDC + nf * 32 + l31] = f2bf(acc[nf][r] * z);
    }
}

// ---------------- K4: y = outT @ Wob^T + bout (16x16x32, 64B-run stores) ----
__global__ __launch_bounds__(256) void k_y(
    const unsigned short* __restrict__ outT,  // B x 4096 x 512
    const unsigned short* __restrict__ Wob,   // 256 x 512
    const float* __restrict__ bout,
    float* __restrict__ y)                    // B x 256 x 4096
{
    const int b  = blockIdx.z;
    const int m0 = blockIdx.x * 128;
    const int n0 = blockIdx.y * 128;
    const int t = threadIdx.x;
    const int wave = t >> 6, lane = t & 63;
    const int wm = wave >> 1, wn = wave & 1;
    const int lrow = lane & 15, quad = lane >> 4;

    __shared__ unsigned short As[128 * LS1];
    __shared__ unsigned short Bs[128 * LS1];

    const unsigned short* Ag = outT + ((size_t)b * NPIX + m0) * HIDC;
    const unsigned short* Bg = Wob + (size_t)n0 * HIDC;

    f32x4 acc[4][4];
#pragma unroll
    for (int i = 0; i < 4; i++)
#pragma unroll
        for (int j = 0; j < 4; j++) acc[i][j] = (f32x4){0.f, 0.f, 0.f, 0.f};

    const int srow = t >> 2, sc8 = (t & 3) * 8;
    for (int k0 = 0; k0 < HIDC; k0 += 32) {
        *(uint4*)&As[srow * LS1 + sc8] =
            *(const uint4*)&Ag[(size_t)srow * HIDC + k0 + sc8];
        *(uint4*)&As[(srow + 64) * LS1 + sc8] =
            *(const uint4*)&Ag[(size_t)(srow + 64) * HIDC + k0 + sc8];
        *(uint4*)&Bs[srow * LS1 + sc8] =
            *(const uint4*)&Bg[(size_t)srow * HIDC + k0 + sc8];
        *(uint4*)&Bs[(srow + 64) * LS1 + sc8] =
            *(const uint4*)&Bg[(size_t)(srow + 64) * HIDC + k0 + sc8];
        __syncthreads();
        bf16x8 af[4], bfr[4];
#pragma unroll
        for (int mt = 0; mt < 4; mt++)
            af[mt] = *(const bf16x8*)&As[(wm * 64 + mt * 16 + lrow) * LS1 + quad * 8];
#pragma unroll
        for (int nt = 0; nt < 4; nt++)
            bfr[nt] = *(const bf16x8*)&Bs[(wn * 64 + nt * 16 + lrow) * LS1 + quad * 8];
#pragma unroll
        for (int mt = 0; mt < 4; mt++)
#pragma unroll
            for (int nt = 0; nt < 4; nt++)
                acc[mt][nt] = __builtin_amdgcn_mfma_f32_16x16x32_bf16(
                    af[mt], bfr[nt], acc[mt][nt], 0, 0, 0);
        __syncthreads();
    }

#pragma unroll
    for (int mt = 0; mt < 4; mt++) {
        const int pixel0 = m0 + wm * 64 + mt * 16 + quad * 4;
#pragma unroll
        for (int nt = 0; nt < 4; nt++) {
            const int o = n0 + wn * 64 + nt * 16 + lrow;
            const float bias = bout[o];
            f32x4 a = acc[mt][nt];
            float4 st; st.x = a[0] + bias; st.y = a[1] + bias;
            st.z = a[2] + bias; st.w = a[3] + bias;
            *(float4*)&y[((size_t)b * DIMC + o) * NPIX + pixel0] = st;
        }
    }
}

extern "C" void kernel_launch(void* const* d_in, const int* in_sizes, int n_in,
                              void* d_out, int out_size, void* d_ws, size_t ws_size,
                              hipStream_t stream) {
    (void)in_sizes; (void)n_in; (void)out_size; (void)ws_size;
    const float* x    = (const float*)d_in[0];
    const float* cm   = (const float*)d_in[1];
    const float* Wqkv = (const float*)d_in[2];
    const float* Wout = (const float*)d_in[3];
    const float* bout = (const float*)d_in[4];
    const float* csp  = (const float*)d_in[5];
    float* y = (float*)d_out;

    const size_t qn = (size_t)BATCH * HIDC * NPIX;
    char* ws = (char*)d_ws;
    unsigned short* qT   = (unsigned short*)ws;                 ws += qn * 2;
    unsigned short* kb   = (unsigned short*)ws;                 ws += qn * 2;
    unsigned short* vb   = (unsigned short*)ws;                 ws += qn * 2;
    unsigned short* outT = (unsigned short*)ws;                 ws += qn * 2;
    unsigned short* xT   = outT;  // alias OK: k_tx->k_qkv reads xT before k_out writes outT
    float* kvp   = (float*)ws;                                  ws += (size_t)64 * 64 * 64 * 4;
    float* ksump = (float*)ws;                                  ws += (size_t)64 * 64 * 4;
    unsigned short* Wb  = (unsigned short*)ws;                  ws += (size_t)1536 * 256 * 2;
    unsigned short* Wob = (unsigned short*)ws;

    hipMemsetAsync(kvp, 0, ((size_t)64 * 64 * 64 + 64 * 64) * sizeof(float), stream);
    k_convW<<<512, 256, 0, stream>>>(Wqkv, Wout, Wb, Wob);
    k_tx  <<<dim3(128, 8, 8), 256, 0, stream>>>(x, xT);
    k_qkv <<<dim3(32, 12, 8), 256, 0, stream>>>(xT, Wb, cm, csp, qT, kb, vb);
    k_kv  <<<dim3(8, 64),     256, 0, stream>>>(kb, vb, kvp, ksump);
    k_out <<<dim3(32, 64),    256, 0, stream>>>(qT, kvp, ksump, outT);
    k_y   <<<dim3(32, 2, 8),  256, 0, stream>>>(outT, Wob, bout, y);
}

// Round 4
// 206.268 us; speedup vs baseline: 2.9063x; 1.0412x over previous
//
#include <hip/hip_runtime.h>
#include <stdint.h>

// LinearAttention MI355X round 4: global_load_lds (16B) staging with XOR-swizzled
// LDS chunks for k_qkv and k_y, BK=64. 32x32x16 MFMA + per-section operand swap
// retained from R3 (full-sector stores).
// B=8, DIM=256, HEADS=8, DHEAD=64, HID=512, NPIX=4096.

#define NPIX 4096
#define HIDC 512
#define DIMC 256
#define BATCH 8

typedef __attribute__((ext_vector_type(8))) short bf16x8;
typedef __attribute__((ext_vector_type(4))) float f32x4;
typedef __attribute__((ext_vector_type(16))) float f32x16;

__device__ __forceinline__ float bf2f(unsigned short h) {
    unsigned int u = ((unsigned int)h) << 16; float f;
    __builtin_memcpy(&f, &u, 4); return f;
}
__device__ __forceinline__ unsigned short f2bf(float f) {
    unsigned int u; __builtin_memcpy(&u, &f, 4);
    u += 0x7fffu + ((u >> 16) & 1u);
    return (unsigned short)(u >> 16);
}
__device__ __forceinline__ float elu1(float x) {
    return x > 0.f ? x + 1.f : __expf(x);
}
// async global->LDS, 16B per lane. LDS dest = wave-uniform base + lane*16.
__device__ __forceinline__ void gl16(const unsigned short* g, unsigned short* l) {
    __builtin_amdgcn_global_load_lds(
        (__attribute__((address_space(1))) const void*)g,
        (__attribute__((address_space(3))) void*)l, 16, 0, 0);
}

// ---------------- K0a: weight conversion ----------------
__global__ __launch_bounds__(256) void k_convW(
    const float* __restrict__ Wqkv, const float* __restrict__ Wout,
    unsigned short* __restrict__ Wb, unsigned short* __restrict__ Wob)
{
    int i4 = (blockIdx.x * 256 + threadIdx.x) * 4;
    const int NW1 = 1536 * 256;
    float4 v; unsigned short* dst;
    if (i4 < NW1) { v = *(const float4*)&Wqkv[i4]; dst = Wb + i4; }
    else { int j = i4 - NW1; v = *(const float4*)&Wout[j]; dst = Wob + j; }
    ushort4 o; o.x = f2bf(v.x); o.y = f2bf(v.y); o.z = f2bf(v.z); o.w = f2bf(v.w);
    *(ushort4*)dst = o;
}

// ---------------- K0b: x transpose+convert ----------------
__global__ __launch_bounds__(256) void k_tx(
    const float* __restrict__ x, unsigned short* __restrict__ xT)
{
    __shared__ float tile[32][33];
    const int n0 = blockIdx.x * 32, c0 = blockIdx.y * 32, b = blockIdx.z;
    const int t = threadIdx.x;
    const int r = t >> 3, c4 = (t & 7) * 4;
    float4 v = *(const float4*)&x[((size_t)b * DIMC + c0 + r) * NPIX + n0 + c4];
    tile[r][c4 + 0] = v.x; tile[r][c4 + 1] = v.y;
    tile[r][c4 + 2] = v.z; tile[r][c4 + 3] = v.w;
    __syncthreads();
    ushort4 o;
    unsigned short* op = (unsigned short*)&o;
#pragma unroll
    for (int i = 0; i < 4; i++) op[i] = f2bf(tile[c4 + i][r]);
    *(ushort4*)&xT[((size_t)b * NPIX + n0 + r) * DIMC + c0 + c4] = o;
}

// ---------------- K1: qkv MFMA GEMM (32x32x16, async staging, BK=64) --------
// grid (32 pixel-tiles, 12 o-tiles, 8 b), block 256 (4 waves, 2x2 of 64x64).
// LDS tile: 128 rows x 64 ushorts, 16B chunks XOR-swizzled: (row,c) holds
// global chunk c ^ (row&7).
__global__ __launch_bounds__(256) void k_qkv(
    const unsigned short* __restrict__ xT,   // B x 4096 x 256
    const unsigned short* __restrict__ Wb,   // 1536 x 256
    const float* __restrict__ cmp,           // B x 4096
    const float* __restrict__ csp,
    unsigned short* __restrict__ qT,         // B x 4096 x 512 (pixel-major)
    unsigned short* __restrict__ kb,         // B x 512 x 4096 (channel-major)
    unsigned short* __restrict__ vb)         // B x 512 x 4096
{
    const int b  = blockIdx.z;
    const int m0 = blockIdx.x * 128;   // pixel tile
    const int n0 = blockIdx.y * 128;   // o tile
    const int t = threadIdx.x;
    const int wave = t >> 6, lane = t & 63;
    const int wm = wave >> 1, wn = wave & 1;
    const int l31 = lane & 31, lhi = lane >> 5;
    const int sect = n0 >> 9;          // 0=q, 1=k, 2=v (block-uniform)

    __shared__ unsigned short As[128 * 64];  // xT tile [pixel][64k]
    __shared__ unsigned short Bs[128 * 64];  // W tile  [o][64k]

    const unsigned short* Ag = xT + ((size_t)b * NPIX + m0) * DIMC;
    const unsigned short* Bg = Wb + (size_t)n0 * DIMC;

    const unsigned short* mArr = (sect == 0) ? As : Bs;
    const unsigned short* nArr = (sect == 0) ? Bs : As;

    f32x16 acc[2][2];
#pragma unroll
    for (int i = 0; i < 2; i++)
#pragma unroll
        for (int j = 0; j < 2; j++)
#pragma unroll
            for (int r = 0; r < 16; r++) acc[i][j][r] = 0.f;

    const int r8  = lane >> 3;                       // row within 8-row group
    const int jg8 = (((lane & 7) ^ r8) & 7) * 8;     // swizzled global chunk (ushorts)
    const int xsw = (l31 & 7);                       // frag-read XOR term

    for (int k0 = 0; k0 < DIMC; k0 += 64) {
#pragma unroll
        for (int i = 0; i < 4; i++) {
            const int rowg = wave * 32 + i * 8;
            gl16(&Ag[(size_t)(rowg + r8) * DIMC + k0 + jg8], &As[rowg * 64]);
            gl16(&Bg[(size_t)(rowg + r8) * DIMC + k0 + jg8], &Bs[rowg * 64]);
        }
        __syncthreads();
#pragma unroll
        for (int ks = 0; ks < 4; ks++) {
            const int coff = ((ks * 2 + lhi) ^ xsw) * 8;
            bf16x8 af[2], bfg[2];
#pragma unroll
            for (int fm = 0; fm < 2; fm++)
                af[fm] = *(const bf16x8*)&mArr[(wm * 64 + fm * 32 + l31) * 64 + coff];
#pragma unroll
            for (int fn = 0; fn < 2; fn++)
                bfg[fn] = *(const bf16x8*)&nArr[(wn * 64 + fn * 32 + l31) * 64 + coff];
#pragma unroll
            for (int fm = 0; fm < 2; fm++)
#pragma unroll
                for (int fn = 0; fn < 2; fn++)
                    acc[fm][fn] = __builtin_amdgcn_mfma_f32_32x32x16_bf16(
                        af[fm], bfg[fn], acc[fm][fn], 0, 0, 0);
        }
        __syncthreads();
    }

    const float cs = *csp;
    if (sect == 0) {
#pragma unroll
        for (int fm = 0; fm < 2; fm++) {
            const int pbase = m0 + wm * 64 + fm * 32;
#pragma unroll
            for (int fn = 0; fn < 2; fn++) {
                const int o = n0 + wn * 64 + fn * 32 + l31;
#pragma unroll
                for (int r = 0; r < 16; r++) {
                    int prow = pbase + (r & 3) + 8 * (r >> 2) + 4 * lhi;
                    qT[((size_t)b * NPIX + prow) * HIDC + o] = f2bf(elu1(acc[fm][fn][r]));
                }
            }
        }
    } else {
        unsigned short* dstb = (sect == 1) ? kb : vb;
#pragma unroll
        for (int fm = 0; fm < 2; fm++) {
            const int obase = (n0 & 511) + wm * 64 + fm * 32;
#pragma unroll
            for (int fn = 0; fn < 2; fn++) {
                const int pixel = m0 + wn * 64 + fn * 32 + l31;
                float g = 1.f;
                if (sect == 1) g = 1.f + cs * cmp[(size_t)b * NPIX + pixel];
#pragma unroll
                for (int r = 0; r < 16; r++) {
                    int orow = obase + (r & 3) + 8 * (r >> 2) + 4 * lhi;
                    float val = acc[fm][fn][r];
                    if (sect == 1) val = elu1(val) * g;
                    dstb[((size_t)b * HIDC + orow) * NPIX + pixel] = f2bf(val);
                }
            }
        }
    }
}

// ---------------- K2: kv + ksum (MFMA over n), channel-major k/v ----------
#define LS2 40
__global__ __launch_bounds__(256) void k_kv(
    const unsigned short* __restrict__ kb, const unsigned short* __restrict__ vb,
    float* __restrict__ kv, float* __restrict__ ksum)
{
    const int bh = blockIdx.y, nc = blockIdx.x;
    const int t = threadIdx.x, wave = t >> 6, lane = t & 63;
    const int lrow = lane & 15, quad = lane >> 4;

    __shared__ unsigned short ks[64 * LS2];
    __shared__ unsigned short vs[64 * LS2];

    const size_t base = (size_t)bh * 64 * NPIX;
    f32x4 acc[4];
#pragma unroll
    for (int i = 0; i < 4; i++) acc[i] = (f32x4){0.f, 0.f, 0.f, 0.f};
    float ksacc = 0.f;

    const int row = t >> 2, c8 = (t & 3) * 8;

    for (int step = 0; step < 16; step++) {
        const int ncol = nc * 512 + step * 32;
        uint4 kq = *(const uint4*)&kb[base + (size_t)row * NPIX + ncol + c8];
        *(uint4*)&ks[row * LS2 + c8] = kq;
        *(uint4*)&vs[row * LS2 + c8] = *(const uint4*)&vb[base + (size_t)row * NPIX + ncol + c8];
        const unsigned short* kp = (const unsigned short*)&kq;
#pragma unroll
        for (int j = 0; j < 8; j++) ksacc += bf2f(kp[j]);
        __syncthreads();
        bf16x8 bfv = *(const bf16x8*)&vs[(wave * 16 + lrow) * LS2 + quad * 8];
#pragma unroll
        for (int mt = 0; mt < 4; mt++) {
            bf16x8 af = *(const bf16x8*)&ks[(mt * 16 + lrow) * LS2 + quad * 8];
            acc[mt] = __builtin_amdgcn_mfma_f32_16x16x32_bf16(af, bfv, acc[mt], 0, 0, 0);
        }
        __syncthreads();
    }

    float* kvb = kv + (size_t)bh * 4096;
#pragma unroll
    for (int mt = 0; mt < 4; mt++)
#pragma unroll
        for (int r = 0; r < 4; r++)
            atomicAdd(&kvb[(mt * 16 + quad * 4 + r) * 64 + wave * 16 + lrow], acc[mt][r]);
    atomicAdd(&ksum[bh * 64 + row], ksacc);
}

// ---------------- K3: out = z * kv^T q  (32x32x16, K=d=64) ----------------
#define LS3 72
__global__ __launch_bounds__(256) void k_out(
    const unsigned short* __restrict__ qT,   // B x 4096 x 512
    const float* __restrict__ kv, const float* __restrict__ ksum,
    unsigned short* __restrict__ outT)       // B x 4096 x 512
{
    const int bh = blockIdx.y, p0 = blockIdx.x * 128;
    const int b = bh >> 3, h = bh & 7;
    const int t = threadIdx.x, wave = t >> 6, lane = t & 63;
    const int l31 = lane & 31, lhi = lane >> 5;

    __shared__ unsigned short Aq[128 * LS3];  // [pixel][d]
    __shared__ unsigned short Bv[96 * LS3];   // [n][d]: 0..63 kvT, 64 hi, 65 lo, 66..95 zero

    const unsigned short* qg = qT + ((size_t)b * NPIX + p0) * HIDC + h * 64;
#pragma unroll
    for (int i = 0; i < 4; i++) {
        int idx = t + i * 256;
        int row = idx >> 3, c8 = (idx & 7) * 8;
        *(uint4*)&Aq[row * LS3 + c8] = *(const uint4*)&qg[(size_t)row * HIDC + c8];
    }
    const float* kvg = kv + (size_t)bh * 4096;
#pragma unroll
    for (int i = 0; i < 16; i++) {
        int idx = t + i * 256;
        int d = idx >> 6, e = idx & 63;
        Bv[e * LS3 + d] = f2bf(kvg[idx]);
    }
    if (t < 64) {
        float ksv = ksum[bh * 64 + t];
        unsigned short hi = f2bf(ksv);
        Bv[64 * LS3 + t] = hi;
        Bv[65 * LS3 + t] = f2bf(ksv - bf2f(hi));
    }
    for (int i = t; i < 30 * 64; i += 256)
        Bv[(66 + (i >> 6)) * LS3 + (i & 63)] = 0;
    __syncthreads();

    f32x16 acc[3];
#pragma unroll
    for (int j = 0; j < 3; j++)
#pragma unroll
        for (int r = 0; r < 16; r++) acc[j][r] = 0.f;

#pragma unroll
    for (int ksub = 0; ksub < 4; ksub++) {
        const int koff = ksub * 16 + lhi * 8;
        bf16x8 af = *(const bf16x8*)&Aq[(wave * 32 + l31) * LS3 + koff];
#pragma unroll
        for (int nf = 0; nf < 3; nf++) {
            bf16x8 bfg = *(const bf16x8*)&Bv[(nf * 32 + l31) * LS3 + koff];
            acc[nf] = __builtin_amdgcn_mfma_f32_32x32x16_bf16(af, bfg, acc[nf], 0, 0, 0);
        }
    }

    unsigned short* og = outT + ((size_t)b * NPIX + p0 + wave * 32) * HIDC + h * 64;
#pragma unroll
    for (int r = 0; r < 16; r++) {
        float hi = __shfl(acc[2][r], lane & 32);
        float lo = __shfl(acc[2][r], (lane & 32) | 1);
        float z = 1.f / (hi + lo + 1e-6f);
        int prow = (r & 3) + 8 * (r >> 2) + 4 * lhi;
#pragma unroll
        for (int nf = 0; nf < 2; nf++)
            og[(size_t)prow * HIDC + nf * 32 + l31] = f2bf(acc[nf][r] * z);
    }
}

// ---------------- K4: y = outT @ Wob^T + bout (16x16x32, async staging) ------
// grid (32, 2, 8), block 256. BK=64, swizzled LDS as in K1.
__global__ __launch_bounds__(256) void k_y(
    const unsigned short* __restrict__ outT,  // B x 4096 x 512
    const unsigned short* __restrict__ Wob,   // 256 x 512
    const float* __restrict__ bout,
    float* __restrict__ y)                    // B x 256 x 4096
{
    const int b  = blockIdx.z;
    const int m0 = blockIdx.x * 128;
    const int n0 = blockIdx.y * 128;
    const int t = threadIdx.x;
    const int wave = t >> 6, lane = t & 63;
    const int wm = wave >> 1, wn = wave & 1;
    const int lrow = lane & 15, quad = lane >> 4;

    __shared__ unsigned short As[128 * 64];
    __shared__ unsigned short Bs[128 * 64];

    const unsigned short* Ag = outT + ((size_t)b * NPIX + m0) * HIDC;
    const unsigned short* Bg = Wob + (size_t)n0 * HIDC;

    f32x4 acc[4][4];
#pragma unroll
    for (int i = 0; i < 4; i++)
#pragma unroll
        for (int j = 0; j < 4; j++) acc[i][j] = (f32x4){0.f, 0.f, 0.f, 0.f};

    const int r8  = lane >> 3;
    const int jg8 = (((lane & 7) ^ r8) & 7) * 8;
    const int xswA = (lrow & 7);

    for (int k0 = 0; k0 < HIDC; k0 += 64) {
#pragma unroll
        for (int i = 0; i < 4; i++) {
            const int rowg = wave * 32 + i * 8;
            gl16(&Ag[(size_t)(rowg + r8) * HIDC + k0 + jg8], &As[rowg * 64]);
            gl16(&Bg[(size_t)(rowg + r8) * HIDC + k0 + jg8], &Bs[rowg * 64]);
        }
        __syncthreads();
#pragma unroll
        for (int ksb = 0; ksb < 2; ksb++) {
            bf16x8 af[4], bfr[4];
#pragma unroll
            for (int mt = 0; mt < 4; mt++) {
                const int row = wm * 64 + mt * 16 + lrow;
                af[mt] = *(const bf16x8*)&As[row * 64 + (((ksb * 4 + quad) ^ xswA)) * 8];
            }
#pragma unroll
            for (int nt = 0; nt < 4; nt++) {
                const int row = wn * 64 + nt * 16 + lrow;
                bfr[nt] = *(const bf16x8*)&Bs[row * 64 + (((ksb * 4 + quad) ^ xswA)) * 8];
            }
#pragma unroll
            for (int mt = 0; mt < 4; mt++)
#pragma unroll
                for (int nt = 0; nt < 4; nt++)
                    acc[mt][nt] = __builtin_amdgcn_mfma_f32_16x16x32_bf16(
                        af[mt], bfr[nt], acc[mt][nt], 0, 0, 0);
        }
        __syncthreads();
    }

#pragma unroll
    for (int mt = 0; mt < 4; mt++) {
        const int pixel0 = m0 + wm * 64 + mt * 16 + quad * 4;
#pragma unroll
        for (int nt = 0; nt < 4; nt++) {
            const int o = n0 + wn * 64 + nt * 16 + lrow;
            const float bias = bout[o];
            f32x4 a = acc[mt][nt];
            float4 st; st.x = a[0] + bias; st.y = a[1] + bias;
            st.z = a[2] + bias; st.w = a[3] + bias;
            *(float4*)&y[((size_t)b * DIMC + o) * NPIX + pixel0] = st;
        }
    }
}

extern "C" void kernel_launch(void* const* d_in, const int* in_sizes, int n_in,
                              void* d_out, int out_size, void* d_ws, size_t ws_size,
                              hipStream_t stream) {
    (void)in_sizes; (void)n_in; (void)out_size; (void)ws_size;
    const float* x    = (const float*)d_in[0];
    const float* cm   = (const float*)d_in[1];
    const float* Wqkv = (const float*)d_in[2];
    const float* Wout = (const float*)d_in[3];
    const float* bout = (const float*)d_in[4];
    const float* csp  = (const float*)d_in[5];
    float* y = (float*)d_out;

    const size_t qn = (size_t)BATCH * HIDC * NPIX;
    char* ws = (char*)d_ws;
    unsigned short* qT   = (unsigned short*)ws;                 ws += qn * 2;
    unsigned short* kb   = (unsigned short*)ws;                 ws += qn * 2;
    unsigned short* vb   = (unsigned short*)ws;                 ws += qn * 2;
    unsigned short* outT = (unsigned short*)ws;                 ws += qn * 2;
    unsigned short* xT   = outT;  // alias OK: k_tx->k_qkv reads xT before k_out writes outT
    float* kvp   = (float*)ws;                                  ws += (size_t)64 * 64 * 64 * 4;
    float* ksump = (float*)ws;                                  ws += (size_t)64 * 64 * 4;
    unsigned short* Wb  = (unsigned short*)ws;                  ws += (size_t)1536 * 256 * 2;
    unsigned short* Wob = (unsigned short*)ws;

    hipMemsetAsync(kvp, 0, ((size_t)64 * 64 * 64 + 64 * 64) * sizeof(float), stream);
    k_convW<<<512, 256, 0, stream>>>(Wqkv, Wout, Wb, Wob);
    k_tx  <<<dim3(128, 8, 8), 256, 0, stream>>>(x, xT);
    k_qkv <<<dim3(32, 12, 8), 256, 0, stream>>>(xT, Wb, cm, csp, qT, kb, vb);
    k_kv  <<<dim3(8, 64),     256, 0, stream>>>(kb, vb, kvp, ksump);
    k_out <<<dim3(32, 64),    256, 0, stream>>>(qT, kvp, ksump, outT);
    k_y   <<<dim3(32, 2, 8),  256, 0, stream>>>(outT, Wob, bout, y);
}